// Round 13
// baseline (1637.106 us; speedup 1.0000x reference)
//
#include <hip/hip_runtime.h>

#define N_PRE 1024
#define N_POST 2048
#define SEQ_LEN 4096

// Reference-verified numerics (R11/R12 PASS): per C element two fp32 segment
// chains k in [0,512) and [512,1024), ascending, single accumulator each,
// combined rn(S1+S2). stim in {0,1} -> products exact -> FMA == mul+add.
// Scan: v = rn(rn(v*0.9f) + c), fire >= 1.0f, reset 0. DO NOT REORDER.
#define KSPLIT 512

// Blocks FMA contraction through it (non-volatile: no scheduler fence).
__device__ __forceinline__ float opaque(float x) {
  asm("" : "+v"(x));
  return x;
}

__device__ __forceinline__ float load_dyn(const void* p, size_t idx, bool isbf) {
  if (isbf) {
    const unsigned short b = ((const unsigned short*)p)[idx];
    return __uint_as_float(((unsigned int)b) << 16);
  }
  return ((const float*)p)[idx];
}

// Input-dtype sniff (established: weights fp32, stim bf16; kept for safety).
__device__ __forceinline__ int sniff_flags(const void* W, const void* S, int tid,
                                           int* flags_sh) {
  if (tid < 64) {
    const unsigned short* uw = (const unsigned short*)W;
    const float f = fabsf(__uint_as_float(((unsigned int)uw[tid * 2]) << 16));
    const bool big = !(f < 64.f);
    const unsigned long long wb = __ballot(big);
    const unsigned short* us = (const unsigned short*)S;
    int hit = 0;
    for (int j = 0; j < 64; ++j) hit |= (us[tid * 128 + 2 * j] == 0x3F80u) ? 1 : 0;
    const unsigned long long sb = __ballot(hit != 0);
    if (tid == 0) *flags_sh = ((wb == 0ull) ? 1 : 0) | ((sb != 0ull) ? 2 : 0);
  }
  __syncthreads();
  return *flags_sh;
}

// ---------------- GEMM v3: 128x128, 8x8 microtile, LDS dbuf, [512|512] ------
__global__ __launch_bounds__(256, 2) void snn_gemm_v3(const void* __restrict__ W,
                                                      const void* __restrict__ S,
                                                      float* __restrict__ C,
                                                      int t0, int chunkT) {
  __shared__ float As[2][16][132];  // [buf][k][m]
  __shared__ float Bs[2][16][132];  // [buf][k][t]
  __shared__ int flags_sh;
  const int tid = threadIdx.x;
  const int fl = sniff_flags(W, S, tid, &flags_sh);
  const bool w_bf = (fl & 1) != 0;
  const bool s_bf = (fl & 2) != 0;

  const int tx = tid & 15;   // t dim
  const int ty = tid >> 4;   // m dim
  const int m0 = blockIdx.y * 128;
  const int nl0 = blockIdx.x * 128;

  // staging thread mapping
  const int arow = tid >> 2;        // 0..63 (W row within half-tile)
  const int ac4 = (tid & 3) * 4;    // k sub-col
  const int br = tid >> 4;          // 0..15 (S row = k)
  const int bc8 = (tid & 15) * 8;   // t sub-col

  float acc0[8][8] = {{0.f}};
  float acc1[8][8] = {{0.f}};
  float4 aR0, aR1;
  uint4 bRa, bRb;

#define GLOAD(KT)                                                                \
  {                                                                              \
    const int k0 = (KT) * 16;                                                    \
    if (!w_bf) {                                                                 \
      const float* Wf = (const float*)W;                                         \
      aR0 = *(const float4*)&Wf[(size_t)(m0 + arow) * N_PRE + k0 + ac4];         \
      aR1 = *(const float4*)&Wf[(size_t)(m0 + arow + 64) * N_PRE + k0 + ac4];    \
    }                                                                            \
    if (s_bf) {                                                                  \
      const unsigned short* Sb = (const unsigned short*)S;                       \
      bRa = *(const uint4*)&Sb[(size_t)(k0 + br) * SEQ_LEN + t0 + nl0 + bc8];    \
    } else {                                                                     \
      const float* Sf = (const float*)S;                                         \
      const size_t base = (size_t)(k0 + br) * SEQ_LEN + t0 + nl0 + bc8;          \
      bRa = *(const uint4*)&Sf[base];                                            \
      bRb = *(const uint4*)&Sf[base + 4];                                        \
    }                                                                            \
  }

#define LSTORE(BUF, KT)                                                          \
  {                                                                              \
    if (!w_bf) {                                                                 \
      As[BUF][ac4 + 0][arow] = aR0.x; As[BUF][ac4 + 1][arow] = aR0.y;            \
      As[BUF][ac4 + 2][arow] = aR0.z; As[BUF][ac4 + 3][arow] = aR0.w;            \
      As[BUF][ac4 + 0][arow + 64] = aR1.x; As[BUF][ac4 + 1][arow + 64] = aR1.y;  \
      As[BUF][ac4 + 2][arow + 64] = aR1.z; As[BUF][ac4 + 3][arow + 64] = aR1.w;  \
    } else {                                                                     \
      const int k0 = (KT) * 16;                                                  \
      _Pragma("unroll") for (int e = 0; e < 8; ++e) {                            \
        const int idx = tid * 8 + e;                                             \
        const int m = idx >> 4, c = idx & 15;                                    \
        As[BUF][c][m] = load_dyn(W, (size_t)(m0 + m) * N_PRE + k0 + c, true);    \
      }                                                                          \
    }                                                                            \
    if (s_bf) {                                                                  \
      float4 f0, f1;                                                             \
      f0.x = __uint_as_float(bRa.x << 16);                                       \
      f0.y = __uint_as_float(bRa.x & 0xFFFF0000u);                               \
      f0.z = __uint_as_float(bRa.y << 16);                                       \
      f0.w = __uint_as_float(bRa.y & 0xFFFF0000u);                               \
      f1.x = __uint_as_float(bRa.z << 16);                                       \
      f1.y = __uint_as_float(bRa.z & 0xFFFF0000u);                               \
      f1.z = __uint_as_float(bRa.w << 16);                                       \
      f1.w = __uint_as_float(bRa.w & 0xFFFF0000u);                               \
      *(float4*)&Bs[BUF][br][bc8] = f0;                                          \
      *(float4*)&Bs[BUF][br][bc8 + 4] = f1;                                      \
    } else {                                                                     \
      *(uint4*)&Bs[BUF][br][bc8] = bRa;                                          \
      *(uint4*)&Bs[BUF][br][bc8 + 4] = bRb;                                      \
    }                                                                            \
  }

#define COMPUTE(BUF, ACC)                                                        \
  {                                                                              \
    _Pragma("unroll") for (int k = 0; k < 16; ++k) {                             \
      float a[8], b[8];                                                          \
      *(float4*)&a[0] = *(const float4*)&As[BUF][k][ty * 8];                     \
      *(float4*)&a[4] = *(const float4*)&As[BUF][k][ty * 8 + 4];                 \
      *(float4*)&b[0] = *(const float4*)&Bs[BUF][k][tx * 4];       /* cols tx*4   */ \
      *(float4*)&b[4] = *(const float4*)&Bs[BUF][k][64 + tx * 4];  /* cols 64+tx*4*/ \
      _Pragma("unroll") for (int i = 0; i < 8; ++i)                              \
          _Pragma("unroll") for (int j = 0; j < 8; ++j)                          \
              ACC[i][j] += a[i] * b[j]; /* exact product: add-chain only */      \
    }                                                                            \
  }

  // prologue: stage k-tile 0
  GLOAD(0)
  LSTORE(0, 0)
  __syncthreads();

  int kt = 0;
#define STEP(ACC)                                                                \
  {                                                                              \
    const int buf = kt & 1;                                                      \
    if (kt + 1 < 64) GLOAD(kt + 1)                                               \
    COMPUTE(buf, ACC)                                                            \
    if (kt + 1 < 64) LSTORE(buf ^ 1, kt + 1)                                     \
    __syncthreads();                                                             \
    ++kt;                                                                        \
  }

  for (int i = 0; i < 32; ++i) STEP(acc0)  // k in [0,512)
  for (int i = 0; i < 32; ++i) STEP(acc1)  // k in [512,1024)
#undef STEP
#undef COMPUTE
#undef LSTORE
#undef GLOAD

#pragma unroll
  for (int i = 0; i < 8; ++i) {
    float4 r0, r1;
    r0.x = acc0[i][0] + acc1[i][0]; r0.y = acc0[i][1] + acc1[i][1];
    r0.z = acc0[i][2] + acc1[i][2]; r0.w = acc0[i][3] + acc1[i][3];
    r1.x = acc0[i][4] + acc1[i][4]; r1.y = acc0[i][5] + acc1[i][5];
    r1.z = acc0[i][6] + acc1[i][6]; r1.w = acc0[i][7] + acc1[i][7];
    float* dst = &C[(size_t)(m0 + ty * 8 + i) * chunkT + nl0 + tx * 4];
    *(float4*)&dst[0] = r0;
    *(float4*)&dst[64] = r1;
  }
}

// ---------------- Scan v3: single-wave blocks, no barriers ------------------
// 128 blocks x 64 threads; 16 neurons/block (lanes 0..15 scan), all 64 lanes
// stage/store. Intra-wave program order + waitcnt replaces __syncthreads.
#define STT 64
__global__ __launch_bounds__(64) void snn_scan_v3(const float* __restrict__ cur,
                                                  float* __restrict__ spk,
                                                  float* __restrict__ vout,
                                                  float* __restrict__ v_carry,
                                                  int t0, int chunkT, int first) {
  __shared__ float c_t[2][16][STT + 4];
  __shared__ float s_t[16][STT + 4];
  __shared__ float v_t[16][STT + 4];
  const int tid = threadIdx.x;      // 0..63
  const int n0 = blockIdx.x * 16;
  const int row = tid >> 2;         // 0..15
  const int cq = (tid & 3) * 16;    // 0,16,32,48

  float v0 = 0.0f;
  if (tid < 16 && !first) v0 = v_carry[n0 + tid];
  // loop-carried "leak" (= rn(v*0.9f), with reset folded: rn(0*0.9f)==0)
  float leak = opaque(v0 * 0.9f);
  float vpost = v0;

  const int nt = chunkT / STT;
  // prologue: tile 0 -> c_t[0]
  {
    const float* src = &cur[(size_t)(n0 + row) * chunkT + cq];
#pragma unroll
    for (int u = 0; u < 4; ++u) *(float4*)&c_t[0][row][cq + 4 * u] = *(const float4*)&src[4 * u];
  }

  for (int it = 0; it < nt; ++it) {
    const int buf = it & 1;
    float4 p0, p1, p2, p3;
    const bool pf = (it + 1 < nt);
    if (pf) {  // issue prefetch loads (land in regs; LDS write deferred)
      const float* src = &cur[(size_t)(n0 + row) * chunkT + (it + 1) * STT + cq];
      p0 = *(const float4*)&src[0];
      p1 = *(const float4*)&src[4];
      p2 = *(const float4*)&src[8];
      p3 = *(const float4*)&src[12];
    }
    if (tid < 16) {
#pragma unroll
      for (int g = 0; g < 4; ++g) {
        float c[16], s[16], vv[16];
        *(float4*)&c[0] = *(const float4*)&c_t[buf][tid][g * 16];
        *(float4*)&c[4] = *(const float4*)&c_t[buf][tid][g * 16 + 4];
        *(float4*)&c[8] = *(const float4*)&c_t[buf][tid][g * 16 + 8];
        *(float4*)&c[12] = *(const float4*)&c_t[buf][tid][g * 16 + 12];
#pragma unroll
        for (int k = 0; k < 16; ++k) {
          const float vpre = leak + c[k];        // rn(leak + c)
          const bool fired = (vpre >= 1.0f);
          const float m = opaque(vpre * 0.9f);   // rn(vpre*0.9f), off reset path
          s[k] = fired ? 1.0f : 0.0f;
          vpost = fired ? 0.0f : vpre;
          vv[k] = vpost;
          leak = fired ? 0.0f : m;               // == rn(vpost*0.9f) exactly
        }
        *(float4*)&s_t[tid][g * 16] = make_float4(s[0], s[1], s[2], s[3]);
        *(float4*)&s_t[tid][g * 16 + 4] = make_float4(s[4], s[5], s[6], s[7]);
        *(float4*)&s_t[tid][g * 16 + 8] = make_float4(s[8], s[9], s[10], s[11]);
        *(float4*)&s_t[tid][g * 16 + 12] = make_float4(s[12], s[13], s[14], s[15]);
        *(float4*)&v_t[tid][g * 16] = make_float4(vv[0], vv[1], vv[2], vv[3]);
        *(float4*)&v_t[tid][g * 16 + 4] = make_float4(vv[4], vv[5], vv[6], vv[7]);
        *(float4*)&v_t[tid][g * 16 + 8] = make_float4(vv[8], vv[9], vv[10], vv[11]);
        *(float4*)&v_t[tid][g * 16 + 12] = make_float4(vv[12], vv[13], vv[14], vv[15]);
      }
    }
    if (pf) {  // land prefetch into the other buffer (read next iteration)
      *(float4*)&c_t[buf ^ 1][row][cq] = p0;
      *(float4*)&c_t[buf ^ 1][row][cq + 4] = p1;
      *(float4*)&c_t[buf ^ 1][row][cq + 8] = p2;
      *(float4*)&c_t[buf ^ 1][row][cq + 12] = p3;
    }
    {  // coalesced stores by all 64 lanes
      const size_t g = (size_t)(n0 + row) * SEQ_LEN + t0 + it * STT + cq;
#pragma unroll
      for (int u = 0; u < 4; ++u) {
        *(float4*)&spk[g + 4 * u] = *(const float4*)&s_t[row][cq + 4 * u];
        *(float4*)&vout[g + 4 * u] = *(const float4*)&v_t[row][cq + 4 * u];
      }
    }
  }

  if (tid < 16) v_carry[n0 + tid] = vpost;
}

// ---------------- fused fallback (ws too small), same [512|512] chain -------
__global__ __launch_bounds__(256) void snn_fused_blis(const void* __restrict__ W,
                                                      const void* __restrict__ S,
                                                      float* __restrict__ spk,
                                                      float* __restrict__ vout) {
  __shared__ float As[16][68];
  __shared__ float Bs[16][68];
  __shared__ float Ct[64][65];
  __shared__ float vsh[64];
  __shared__ int flags_sh;
  const int tid = threadIdx.x;
  const int fl = sniff_flags(W, S, tid, &flags_sh);
  const bool w_bf = (fl & 1) != 0;
  const bool s_bf = (fl & 2) != 0;

  const int tx = tid & 15;
  const int ty = tid >> 4;
  const int m0 = blockIdx.x * 64;
  if (tid < 64) vsh[tid] = 0.0f;

  for (int t0 = 0; t0 < SEQ_LEN; t0 += 64) {
    float acc0[4][4] = {{0.f}};
    float acc1[4][4] = {{0.f}};
    int k0 = 0;
#define FUSED_SEGMENT(ACC, KEND)                                                 \
    for (; k0 < (KEND); k0 += 16) {                                              \
      {                                                                          \
        const int r = tid >> 4, c = tid & 15;                                    \
        _Pragma("unroll") for (int j = 0; j < 4; ++j)                            \
            As[c][r + 16 * j] =                                                  \
                load_dyn(W, (size_t)(m0 + r + 16 * j) * N_PRE + k0 + c, w_bf);   \
      }                                                                          \
      {                                                                          \
        const int r = tid >> 6, c = tid & 63;                                    \
        _Pragma("unroll") for (int j = 0; j < 4; ++j)                            \
            Bs[r + 4 * j][c] =                                                   \
                load_dyn(S, (size_t)(k0 + r + 4 * j) * SEQ_LEN + t0 + c, s_bf);  \
      }                                                                          \
      __syncthreads();                                                           \
      _Pragma("unroll") for (int k = 0; k < 16; ++k) {                           \
        _Pragma("unroll") for (int i = 0; i < 4; ++i)                            \
            _Pragma("unroll") for (int j = 0; j < 4; ++j)                        \
                ACC[i][j] += As[k][ty * 4 + i] * Bs[k][tx * 4 + j];              \
      }                                                                          \
      __syncthreads();                                                           \
    }

    FUSED_SEGMENT(acc0, KSPLIT)
    FUSED_SEGMENT(acc1, N_PRE)
#undef FUSED_SEGMENT

#pragma unroll
    for (int i = 0; i < 4; ++i)
#pragma unroll
      for (int j = 0; j < 4; ++j) Ct[ty * 4 + i][tx * 4 + j] = acc0[i][j] + acc1[i][j];
    __syncthreads();
    if (tid < 64) {
      float v = vsh[tid];
#pragma unroll
      for (int k = 0; k < 64; ++k) {
        const float leak = opaque(v * 0.9f);
        v = leak + Ct[tid][k];
        const bool fired = (v >= 1.0f);
        const size_t g = (size_t)(m0 + tid) * SEQ_LEN + t0 + k;
        spk[g] = fired ? 1.0f : 0.0f;
        v = fired ? 0.0f : v;
        vout[g] = v;
      }
      vsh[tid] = v;
    }
    __syncthreads();
  }
}

extern "C" void kernel_launch(void* const* d_in, const int* in_sizes, int n_in,
                              void* d_out, int out_size, void* d_ws, size_t ws_size,
                              hipStream_t stream) {
  const void* stim = d_in[0];
  const void* weights = d_in[1];
  if (n_in >= 2 && in_sizes[0] == N_POST * N_PRE && in_sizes[1] == N_PRE * SEQ_LEN) {
    weights = d_in[0];
    stim = d_in[1];
  }

  float* spk = (float*)d_out;                     // output 0: spikes [N_POST, SEQ_LEN] fp32
  float* vout = spk + (size_t)N_POST * SEQ_LEN;   // output 1: v      [N_POST, SEQ_LEN] fp32

  const size_t carry_bytes = (size_t)N_POST * sizeof(float);
  float* v_carry = nullptr;
  size_t avail = 0;
  if (ws_size > carry_bytes + 8) {
    const size_t coff = (ws_size - carry_bytes) & ~(size_t)15;
    v_carry = (float*)((char*)d_ws + coff);
    avail = coff;
  }
  int chunkT = (int)((avail / ((size_t)N_POST * sizeof(float))) / 128 * 128);
  if (chunkT > SEQ_LEN) chunkT = SEQ_LEN;

  if (chunkT >= 128) {
    float* cur = (float*)d_ws;
    for (int t0 = 0; t0 < SEQ_LEN; t0 += chunkT) {
      const int ct = (SEQ_LEN - t0 < chunkT) ? (SEQ_LEN - t0) : chunkT;  // mult of 128
      snn_gemm_v3<<<dim3(ct / 128, N_POST / 128), dim3(256), 0, stream>>>(weights, stim, cur,
                                                                          t0, ct);
      snn_scan_v3<<<dim3(N_POST / 16), dim3(64), 0, stream>>>(cur, spk, vout, v_carry,
                                                              t0, ct, t0 == 0);
    }
  } else {
    snn_fused_blis<<<dim3(N_POST / 64), dim3(256), 0, stream>>>(weights, stim, spk, vout);
  }
}

// Round 14
// 878.905 us; speedup vs baseline: 1.8627x; 1.8627x over previous
//
#include <hip/hip_runtime.h>

#define N_PRE 1024
#define N_POST 2048
#define SEQ_LEN 4096

// Reference-verified numerics (R11/R12/R13 PASS): per C element two fp32
// segment chains k in [0,512) and [512,1024), ascending, single accumulator
// each, combined rn(S1+S2). stim in {0,1} -> products exact. Scan:
// v = rn(rn(v*0.9f) + c), fire >= 1.0f, reset 0 (reset-folded form verified
// in R13). DO NOT REORDER.
#define KSPLIT 512

// Blocks FMA contraction through it (non-volatile: no scheduler fence).
__device__ __forceinline__ float opaque(float x) {
  asm("" : "+v"(x));
  return x;
}

__device__ __forceinline__ float load_dyn(const void* p, size_t idx, bool isbf) {
  if (isbf) {
    const unsigned short b = ((const unsigned short*)p)[idx];
    return __uint_as_float(((unsigned int)b) << 16);
  }
  return ((const float*)p)[idx];
}

// Input-dtype sniff (established: weights fp32, stim bf16; kept for safety).
__device__ __forceinline__ int sniff_flags(const void* W, const void* S, int tid,
                                           int* flags_sh) {
  if (tid < 64) {
    const unsigned short* uw = (const unsigned short*)W;
    const float f = fabsf(__uint_as_float(((unsigned int)uw[tid * 2]) << 16));
    const bool big = !(f < 64.f);
    const unsigned long long wb = __ballot(big);
    const unsigned short* us = (const unsigned short*)S;
    int hit = 0;
    for (int j = 0; j < 64; ++j) hit |= (us[tid * 128 + 2 * j] == 0x3F80u) ? 1 : 0;
    const unsigned long long sb = __ballot(hit != 0);
    if (tid == 0) *flags_sh = ((wb == 0ull) ? 1 : 0) | ((sb != 0ull) ? 2 : 0);
  }
  __syncthreads();
  return *flags_sh;
}

// ---------------- GEMM segment kernel: 128x128, 8x8 micro, 32 k-tiles -------
// Computes one BLIS K-segment (kbase..kbase+512) into its own buffer C.
// Single acc set (64 VGPRs) + register prefetch of next k-tile; single LDS
// buffer, 2 barriers/tile; global latency hidden behind the 2048-cyc compute.
__global__ __launch_bounds__(256, 3) void snn_gemm_seg(const void* __restrict__ W,
                                                       const void* __restrict__ S,
                                                       float* __restrict__ C,
                                                       int t0, int chunkT, int kbase) {
  __shared__ float As[16][132];  // [k][m], pad 132: 16B rows + 4-bank shift
  __shared__ float Bs[16][132];  // [k][t]
  __shared__ int flags_sh;
  const int tid = threadIdx.x;
  const int fl = sniff_flags(W, S, tid, &flags_sh);
  const bool w_bf = (fl & 1) != 0;
  const bool s_bf = (fl & 2) != 0;

  const int tx = tid & 15;   // t dim
  const int ty = tid >> 4;   // m dim
  const int m0 = blockIdx.y * 128;
  const int nl0 = blockIdx.x * 128;

  // staging mapping
  const int arow = tid >> 2;        // 0..63 (W row within half-tile)
  const int ac4 = (tid & 3) * 4;    // k sub-col
  const int br = tid >> 4;          // 0..15 (S row = k)
  const int bc8 = (tid & 15) * 8;   // t sub-col

  float acc[8][8] = {{0.f}};
  float4 aR0, aR1;
  uint4 bRa, bRb;

#define GLOAD(K0)                                                                \
  {                                                                              \
    if (!w_bf) {                                                                 \
      const float* Wf = (const float*)W;                                         \
      aR0 = *(const float4*)&Wf[(size_t)(m0 + arow) * N_PRE + (K0) + ac4];       \
      aR1 = *(const float4*)&Wf[(size_t)(m0 + arow + 64) * N_PRE + (K0) + ac4];  \
    }                                                                            \
    if (s_bf) {                                                                  \
      const unsigned short* Sb = (const unsigned short*)S;                       \
      bRa = *(const uint4*)&Sb[(size_t)((K0) + br) * SEQ_LEN + t0 + nl0 + bc8];  \
    } else {                                                                     \
      const float* Sf = (const float*)S;                                         \
      const size_t base = (size_t)((K0) + br) * SEQ_LEN + t0 + nl0 + bc8;        \
      bRa = *(const uint4*)&Sf[base];                                            \
      bRb = *(const uint4*)&Sf[base + 4];                                        \
    }                                                                            \
  }

#define LSTORE(K0)                                                               \
  {                                                                              \
    if (!w_bf) {                                                                 \
      As[ac4 + 0][arow] = aR0.x; As[ac4 + 1][arow] = aR0.y;                      \
      As[ac4 + 2][arow] = aR0.z; As[ac4 + 3][arow] = aR0.w;                      \
      As[ac4 + 0][arow + 64] = aR1.x; As[ac4 + 1][arow + 64] = aR1.y;            \
      As[ac4 + 2][arow + 64] = aR1.z; As[ac4 + 3][arow + 64] = aR1.w;            \
    } else {                                                                     \
      _Pragma("unroll") for (int e = 0; e < 8; ++e) {                            \
        const int idx = tid * 8 + e;                                             \
        const int m = idx >> 4, c = idx & 15;                                    \
        As[c][m] = load_dyn(W, (size_t)(m0 + m) * N_PRE + (K0) + c, true);       \
      }                                                                          \
    }                                                                            \
    if (s_bf) {                                                                  \
      float4 f0, f1;                                                             \
      f0.x = __uint_as_float(bRa.x << 16);                                       \
      f0.y = __uint_as_float(bRa.x & 0xFFFF0000u);                               \
      f0.z = __uint_as_float(bRa.y << 16);                                       \
      f0.w = __uint_as_float(bRa.y & 0xFFFF0000u);                               \
      f1.x = __uint_as_float(bRa.z << 16);                                       \
      f1.y = __uint_as_float(bRa.z & 0xFFFF0000u);                               \
      f1.z = __uint_as_float(bRa.w << 16);                                       \
      f1.w = __uint_as_float(bRa.w & 0xFFFF0000u);                               \
      *(float4*)&Bs[br][bc8] = f0;                                               \
      *(float4*)&Bs[br][bc8 + 4] = f1;                                           \
    } else {                                                                     \
      *(uint4*)&Bs[br][bc8] = bRa;                                               \
      *(uint4*)&Bs[br][bc8 + 4] = bRb;                                           \
    }                                                                            \
  }

  // prologue: fetch k-tile 0 of this segment into regs
  GLOAD(kbase)

  for (int kt = 0; kt < 32; ++kt) {
    LSTORE(kbase + kt * 16)
    __syncthreads();
    if (kt + 1 < 32) GLOAD(kbase + (kt + 1) * 16)  // issue early; compute hides it
#pragma unroll
    for (int k = 0; k < 16; ++k) {  // ascending k within tile, tiles ascending
      float a[8], b[8];
      *(float4*)&a[0] = *(const float4*)&As[k][ty * 8];
      *(float4*)&a[4] = *(const float4*)&As[k][ty * 8 + 4];
      *(float4*)&b[0] = *(const float4*)&Bs[k][tx * 4];       // cols tx*4
      *(float4*)&b[4] = *(const float4*)&Bs[k][64 + tx * 4];  // cols 64+tx*4
#pragma unroll
      for (int i = 0; i < 8; ++i)
#pragma unroll
        for (int j = 0; j < 8; ++j) acc[i][j] += a[i] * b[j];  // exact product
    }
    __syncthreads();
  }
#undef LSTORE
#undef GLOAD

  // epilogue: raw segment sums (exact fp32 values, no extra rounding)
#pragma unroll
  for (int i = 0; i < 8; ++i) {
    float* dst = &C[(size_t)(m0 + ty * 8 + i) * chunkT + nl0 + tx * 4];
    *(float4*)&dst[0] = make_float4(acc[i][0], acc[i][1], acc[i][2], acc[i][3]);
    *(float4*)&dst[64] = make_float4(acc[i][4], acc[i][5], acc[i][6], acc[i][7]);
  }
}

// ---------------- Scan v4: single-wave blocks, 2-buffer combine -------------
// 128 blocks x 64 threads; lanes 0..15 scan 16 neurons; all lanes stage/store.
// Combine c = rn(c1+c2) when landing the prefetch (the reference's rn(S1+S2)).
// Group-pipelined LDS reads hide the 120-cyc LDS latency inside the chain.
#define STT 64
__global__ __launch_bounds__(64) void snn_scan_v4(const float* __restrict__ cur1,
                                                  const float* __restrict__ cur2,
                                                  float* __restrict__ spk,
                                                  float* __restrict__ vout,
                                                  float* __restrict__ v_carry,
                                                  int t0, int chunkT, int first) {
  __shared__ float c_t[2][16][STT + 4];
  __shared__ float s_t[16][STT + 4];
  __shared__ float v_t[16][STT + 4];
  const int tid = threadIdx.x;      // 0..63
  const int n0 = blockIdx.x * 16;
  const int row = tid >> 2;         // 0..15
  const int cq = (tid & 3) * 16;    // 0,16,32,48

  float v0 = 0.0f;
  if (tid < 16 && !first) v0 = v_carry[n0 + tid];
  float leak = opaque(v0 * 0.9f);  // rn(v*0.9f); rn(0*0.9f)==0 folds reset
  float vpost = v0;

  const int nt = chunkT / STT;
  // prologue: tile 0 combined -> c_t[0]
  {
    const float* s1 = &cur1[(size_t)(n0 + row) * chunkT + cq];
    const float* s2 = &cur2[(size_t)(n0 + row) * chunkT + cq];
#pragma unroll
    for (int u = 0; u < 4; ++u) {
      const float4 a = *(const float4*)&s1[4 * u];
      const float4 b = *(const float4*)&s2[4 * u];
      *(float4*)&c_t[0][row][cq + 4 * u] =
          make_float4(a.x + b.x, a.y + b.y, a.z + b.z, a.w + b.w);  // rn(S1+S2)
    }
  }

  for (int it = 0; it < nt; ++it) {
    const int buf = it & 1;
    float4 p1[4], p2[4];
    const bool pf = (it + 1 < nt);
    if (pf) {  // issue prefetch loads for next tile (both buffers)
      const float* s1 = &cur1[(size_t)(n0 + row) * chunkT + (it + 1) * STT + cq];
      const float* s2 = &cur2[(size_t)(n0 + row) * chunkT + (it + 1) * STT + cq];
#pragma unroll
      for (int u = 0; u < 4; ++u) {
        p1[u] = *(const float4*)&s1[4 * u];
        p2[u] = *(const float4*)&s2[4 * u];
      }
    }
    if (tid < 16) {
      float cb[2][16];
      // preload group 0
      *(float4*)&cb[0][0] = *(const float4*)&c_t[buf][tid][0];
      *(float4*)&cb[0][4] = *(const float4*)&c_t[buf][tid][4];
      *(float4*)&cb[0][8] = *(const float4*)&c_t[buf][tid][8];
      *(float4*)&cb[0][12] = *(const float4*)&c_t[buf][tid][12];
#pragma unroll
      for (int g = 0; g < 4; ++g) {
        if (g < 3) {  // pipeline: fetch group g+1 while scanning group g
          *(float4*)&cb[(g + 1) & 1][0] = *(const float4*)&c_t[buf][tid][(g + 1) * 16];
          *(float4*)&cb[(g + 1) & 1][4] = *(const float4*)&c_t[buf][tid][(g + 1) * 16 + 4];
          *(float4*)&cb[(g + 1) & 1][8] = *(const float4*)&c_t[buf][tid][(g + 1) * 16 + 8];
          *(float4*)&cb[(g + 1) & 1][12] = *(const float4*)&c_t[buf][tid][(g + 1) * 16 + 12];
        }
        float s[16], vv[16];
        const float* c = cb[g & 1];
#pragma unroll
        for (int k = 0; k < 16; ++k) {
          const float vpre = leak + c[k];        // rn(leak + c)
          const bool fired = (vpre >= 1.0f);
          const float m = opaque(vpre * 0.9f);   // rn(vpre*0.9f), off reset path
          s[k] = fired ? 1.0f : 0.0f;
          vpost = fired ? 0.0f : vpre;
          vv[k] = vpost;
          leak = fired ? 0.0f : m;               // == rn(vpost*0.9f) exactly
        }
        *(float4*)&s_t[tid][g * 16] = make_float4(s[0], s[1], s[2], s[3]);
        *(float4*)&s_t[tid][g * 16 + 4] = make_float4(s[4], s[5], s[6], s[7]);
        *(float4*)&s_t[tid][g * 16 + 8] = make_float4(s[8], s[9], s[10], s[11]);
        *(float4*)&s_t[tid][g * 16 + 12] = make_float4(s[12], s[13], s[14], s[15]);
        *(float4*)&v_t[tid][g * 16] = make_float4(vv[0], vv[1], vv[2], vv[3]);
        *(float4*)&v_t[tid][g * 16 + 4] = make_float4(vv[4], vv[5], vv[6], vv[7]);
        *(float4*)&v_t[tid][g * 16 + 8] = make_float4(vv[8], vv[9], vv[10], vv[11]);
        *(float4*)&v_t[tid][g * 16 + 12] = make_float4(vv[12], vv[13], vv[14], vv[15]);
      }
    }
    if (pf) {  // land combined prefetch into the other buffer
#pragma unroll
      for (int u = 0; u < 4; ++u) {
        *(float4*)&c_t[buf ^ 1][row][cq + 4 * u] =
            make_float4(p1[u].x + p2[u].x, p1[u].y + p2[u].y,
                        p1[u].z + p2[u].z, p1[u].w + p2[u].w);  // rn(S1+S2)
      }
    }
    {  // coalesced stores by all 64 lanes
      const size_t g = (size_t)(n0 + row) * SEQ_LEN + t0 + it * STT + cq;
#pragma unroll
      for (int u = 0; u < 4; ++u) {
        *(float4*)&spk[g + 4 * u] = *(const float4*)&s_t[row][cq + 4 * u];
        *(float4*)&vout[g + 4 * u] = *(const float4*)&v_t[row][cq + 4 * u];
      }
    }
  }

  if (tid < 16) v_carry[n0 + tid] = vpost;
}

// ---------------- fused fallback (ws too small), same [512|512] chain -------
__global__ __launch_bounds__(256) void snn_fused_blis(const void* __restrict__ W,
                                                      const void* __restrict__ S,
                                                      float* __restrict__ spk,
                                                      float* __restrict__ vout) {
  __shared__ float As[16][68];
  __shared__ float Bs[16][68];
  __shared__ float Ct[64][65];
  __shared__ float vsh[64];
  __shared__ int flags_sh;
  const int tid = threadIdx.x;
  const int fl = sniff_flags(W, S, tid, &flags_sh);
  const bool w_bf = (fl & 1) != 0;
  const bool s_bf = (fl & 2) != 0;

  const int tx = tid & 15;
  const int ty = tid >> 4;
  const int m0 = blockIdx.x * 64;
  if (tid < 64) vsh[tid] = 0.0f;

  for (int t0 = 0; t0 < SEQ_LEN; t0 += 64) {
    float acc0[4][4] = {{0.f}};
    float acc1[4][4] = {{0.f}};
    int k0 = 0;
#define FUSED_SEGMENT(ACC, KEND)                                                 \
    for (; k0 < (KEND); k0 += 16) {                                              \
      {                                                                          \
        const int r = tid >> 4, c = tid & 15;                                    \
        _Pragma("unroll") for (int j = 0; j < 4; ++j)                            \
            As[c][r + 16 * j] =                                                  \
                load_dyn(W, (size_t)(m0 + r + 16 * j) * N_PRE + k0 + c, w_bf);   \
      }                                                                          \
      {                                                                          \
        const int r = tid >> 6, c = tid & 63;                                    \
        _Pragma("unroll") for (int j = 0; j < 4; ++j)                            \
            Bs[r + 4 * j][c] =                                                   \
                load_dyn(S, (size_t)(k0 + r + 4 * j) * SEQ_LEN + t0 + c, s_bf);  \
      }                                                                          \
      __syncthreads();                                                           \
      _Pragma("unroll") for (int k = 0; k < 16; ++k) {                           \
        _Pragma("unroll") for (int i = 0; i < 4; ++i)                            \
            _Pragma("unroll") for (int j = 0; j < 4; ++j)                        \
                ACC[i][j] += As[k][ty * 4 + i] * Bs[k][tx * 4 + j];              \
      }                                                                          \
      __syncthreads();                                                           \
    }

    FUSED_SEGMENT(acc0, KSPLIT)
    FUSED_SEGMENT(acc1, N_PRE)
#undef FUSED_SEGMENT

#pragma unroll
    for (int i = 0; i < 4; ++i)
#pragma unroll
      for (int j = 0; j < 4; ++j) Ct[ty * 4 + i][tx * 4 + j] = acc0[i][j] + acc1[i][j];
    __syncthreads();
    if (tid < 64) {
      float v = vsh[tid];
#pragma unroll
      for (int k = 0; k < 64; ++k) {
        const float leak = opaque(v * 0.9f);
        v = leak + Ct[tid][k];
        const bool fired = (v >= 1.0f);
        const size_t g = (size_t)(m0 + tid) * SEQ_LEN + t0 + k;
        spk[g] = fired ? 1.0f : 0.0f;
        v = fired ? 0.0f : v;
        vout[g] = v;
      }
      vsh[tid] = v;
    }
    __syncthreads();
  }
}

extern "C" void kernel_launch(void* const* d_in, const int* in_sizes, int n_in,
                              void* d_out, int out_size, void* d_ws, size_t ws_size,
                              hipStream_t stream) {
  const void* stim = d_in[0];
  const void* weights = d_in[1];
  if (n_in >= 2 && in_sizes[0] == N_POST * N_PRE && in_sizes[1] == N_PRE * SEQ_LEN) {
    weights = d_in[0];
    stim = d_in[1];
  }

  float* spk = (float*)d_out;                     // output 0: spikes [N_POST, SEQ_LEN] fp32
  float* vout = spk + (size_t)N_POST * SEQ_LEN;   // output 1: v      [N_POST, SEQ_LEN] fp32

  // ws layout: [cur1 chunk][cur2 chunk][v_carry 8KB]
  const size_t carry_bytes = (size_t)N_POST * sizeof(float);
  float* v_carry = nullptr;
  size_t avail = 0;
  if (ws_size > carry_bytes + 8) {
    const size_t coff = (ws_size - carry_bytes) & ~(size_t)15;
    v_carry = (float*)((char*)d_ws + coff);
    avail = coff;
  }
  int chunkT = (int)((avail / (2 * (size_t)N_POST * sizeof(float))) / 128 * 128);
  if (chunkT > SEQ_LEN) chunkT = SEQ_LEN;

  if (chunkT >= 128) {
    float* cur1 = (float*)d_ws;
    float* cur2 = cur1 + (size_t)chunkT * N_POST;
    for (int t0 = 0; t0 < SEQ_LEN; t0 += chunkT) {
      const int ct = (SEQ_LEN - t0 < chunkT) ? (SEQ_LEN - t0) : chunkT;  // mult of 128
      dim3 gg(ct / 128, N_POST / 128);
      snn_gemm_seg<<<gg, dim3(256), 0, stream>>>(weights, stim, cur1, t0, ct, 0);
      snn_gemm_seg<<<gg, dim3(256), 0, stream>>>(weights, stim, cur2, t0, ct, KSPLIT);
      snn_scan_v4<<<dim3(N_POST / 16), dim3(64), 0, stream>>>(cur1, cur2, spk, vout,
                                                              v_carry, t0, ct, t0 == 0);
    }
  } else {
    snn_fused_blis<<<dim3(N_POST / 64), dim3(256), 0, stream>>>(weights, stim, spk, vout);
  }
}

// Round 15
// 483.742 us; speedup vs baseline: 3.3843x; 1.8169x over previous
//
#include <hip/hip_runtime.h>

#define N_PRE 1024
#define N_POST 2048
#define SEQ_LEN 4096

// Reference-verified numerics (R11..R14 PASS): per C element two fp32 segment
// chains k in [0,512) and [512,1024), ascending, single accumulator each,
// combined rn(S1+S2). stim in {0,1} -> products exact. Scan:
// v = rn(rn(v*0.9f) + c), fire >= 1.0f, reset 0 (reset-folded form verified).
// DO NOT REORDER.
#define KSPLIT 512

__device__ __forceinline__ float opaque(float x) {
  asm("" : "+v"(x));
  return x;
}

__device__ __forceinline__ float load_dyn(const void* p, size_t idx, bool isbf) {
  if (isbf) {
    const unsigned short b = ((const unsigned short*)p)[idx];
    return __uint_as_float(((unsigned int)b) << 16);
  }
  return ((const float*)p)[idx];
}

// Input-dtype sniff (established: weights fp32, stim bf16; kept for safety).
__device__ __forceinline__ int sniff_flags(const void* W, const void* S, int tid,
                                           int* flags_sh) {
  if (tid < 64) {
    const unsigned short* uw = (const unsigned short*)W;
    const float f = fabsf(__uint_as_float(((unsigned int)uw[tid * 2]) << 16));
    const bool big = !(f < 64.f);
    const unsigned long long wb = __ballot(big);
    const unsigned short* us = (const unsigned short*)S;
    int hit = 0;
    for (int j = 0; j < 64; ++j) hit |= (us[tid * 128 + 2 * j] == 0x3F80u) ? 1 : 0;
    const unsigned long long sb = __ballot(hit != 0);
    if (tid == 0) *flags_sh = ((wb == 0ull) ? 1 : 0) | ((sb != 0ull) ? 2 : 0);
  }
  __syncthreads();
  return *flags_sh;
}

// ---------------- GEMM v5: 128x128, 8x8 micro, sequential segments ----------
// One launch. Per block: seg1 (k 0..511) -> stash tile to C1 (L2 round-trip),
// seg2 (k 512..1023) -> final = rn(C1 + acc) -> Cout. Single 64-reg acc.
// launch_bounds(256,2): empirically the only setting where the compiler
// allocates 128 VGPRs and does NOT spill the accumulator (R12 vs R13/R14).
__global__ __launch_bounds__(256, 2) void snn_gemm_v5(const void* __restrict__ W,
                                                      const void* __restrict__ S,
                                                      float* __restrict__ Cout,
                                                      float* __restrict__ C1,
                                                      int t0, int chunkT) {
  __shared__ float As[16][132];  // [k][m], pad 132: 16B rows + 4-bank shift
  __shared__ float Bs[16][132];  // [k][t]
  __shared__ int flags_sh;
  const int tid = threadIdx.x;
  const int fl = sniff_flags(W, S, tid, &flags_sh);
  const bool w_bf = (fl & 1) != 0;
  const bool s_bf = (fl & 2) != 0;

  const int tx = tid & 15;   // t dim
  const int ty = tid >> 4;   // m dim
  const int m0 = blockIdx.y * 128;
  const int nl0 = blockIdx.x * 128;

  // staging mapping
  const int arow = tid >> 2;        // 0..63 (W row within half-tile)
  const int ac4 = (tid & 3) * 4;    // k sub-col
  const int br = tid >> 4;          // 0..15 (S row = k)
  const int bc8 = (tid & 15) * 8;   // t sub-col

  float acc[8][8];
  float4 aR0, aR1;
  uint4 bRa, bRb;

#define GLOAD(K0)                                                                \
  {                                                                              \
    if (!w_bf) {                                                                 \
      const float* Wf = (const float*)W;                                         \
      aR0 = *(const float4*)&Wf[(size_t)(m0 + arow) * N_PRE + (K0) + ac4];       \
      aR1 = *(const float4*)&Wf[(size_t)(m0 + arow + 64) * N_PRE + (K0) + ac4];  \
    }                                                                            \
    if (s_bf) {                                                                  \
      const unsigned short* Sb = (const unsigned short*)S;                       \
      bRa = *(const uint4*)&Sb[(size_t)((K0) + br) * SEQ_LEN + t0 + nl0 + bc8];  \
    } else {                                                                     \
      const float* Sf = (const float*)S;                                         \
      const size_t base = (size_t)((K0) + br) * SEQ_LEN + t0 + nl0 + bc8;        \
      bRa = *(const uint4*)&Sf[base];                                            \
      bRb = *(const uint4*)&Sf[base + 4];                                        \
    }                                                                            \
  }

#define LSTORE(K0)                                                               \
  {                                                                              \
    if (!w_bf) {                                                                 \
      As[ac4 + 0][arow] = aR0.x; As[ac4 + 1][arow] = aR0.y;                      \
      As[ac4 + 2][arow] = aR0.z; As[ac4 + 3][arow] = aR0.w;                      \
      As[ac4 + 0][arow + 64] = aR1.x; As[ac4 + 1][arow + 64] = aR1.y;            \
      As[ac4 + 2][arow + 64] = aR1.z; As[ac4 + 3][arow + 64] = aR1.w;            \
    } else {                                                                     \
      _Pragma("unroll") for (int e = 0; e < 8; ++e) {                            \
        const int idx = tid * 8 + e;                                             \
        const int m = idx >> 4, c = idx & 15;                                    \
        As[c][m] = load_dyn(W, (size_t)(m0 + m) * N_PRE + (K0) + c, true);       \
      }                                                                          \
    }                                                                            \
    if (s_bf) {                                                                  \
      float4 f0, f1;                                                             \
      f0.x = __uint_as_float(bRa.x << 16);                                       \
      f0.y = __uint_as_float(bRa.x & 0xFFFF0000u);                               \
      f0.z = __uint_as_float(bRa.y << 16);                                       \
      f0.w = __uint_as_float(bRa.y & 0xFFFF0000u);                               \
      f1.x = __uint_as_float(bRa.z << 16);                                       \
      f1.y = __uint_as_float(bRa.z & 0xFFFF0000u);                               \
      f1.z = __uint_as_float(bRa.w << 16);                                       \
      f1.w = __uint_as_float(bRa.w & 0xFFFF0000u);                               \
      *(float4*)&Bs[br][bc8] = f0;                                               \
      *(float4*)&Bs[br][bc8 + 4] = f1;                                           \
    } else {                                                                     \
      *(uint4*)&Bs[br][bc8] = bRa;                                               \
      *(uint4*)&Bs[br][bc8 + 4] = bRb;                                           \
    }                                                                            \
  }

#define SEG_LOOP(KT_BEGIN, KT_END)                                               \
  for (int kt = (KT_BEGIN); kt < (KT_END); ++kt) {                               \
    LSTORE(kt * 16)                                                              \
    __syncthreads();                                                             \
    if (kt + 1 < (KT_END)) GLOAD((kt + 1) * 16)                                  \
    _Pragma("unroll") for (int k = 0; k < 16; ++k) {                             \
      float a[8], b[8];                                                          \
      *(float4*)&a[0] = *(const float4*)&As[k][ty * 8];                          \
      *(float4*)&a[4] = *(const float4*)&As[k][ty * 8 + 4];                      \
      *(float4*)&b[0] = *(const float4*)&Bs[k][tx * 4];                          \
      *(float4*)&b[4] = *(const float4*)&Bs[k][64 + tx * 4];                     \
      _Pragma("unroll") for (int i = 0; i < 8; ++i)                              \
          _Pragma("unroll") for (int j = 0; j < 8; ++j)                          \
              acc[i][j] += a[i] * b[j]; /* exact product: add-chain only */      \
    }                                                                            \
    __syncthreads();                                                             \
  }

  // ---- segment 1: k in [0, 512), ascending ----
#pragma unroll
  for (int i = 0; i < 8; ++i)
#pragma unroll
    for (int j = 0; j < 8; ++j) acc[i][j] = 0.f;
  GLOAD(0)
  SEG_LOOP(0, 32)

  // stash S1 tile (exact fp32 segment sums; same thread reads back)
#pragma unroll
  for (int i = 0; i < 8; ++i) {
    float* dst = &C1[(size_t)(m0 + ty * 8 + i) * chunkT + nl0 + tx * 4];
    *(float4*)&dst[0] = make_float4(acc[i][0], acc[i][1], acc[i][2], acc[i][3]);
    *(float4*)&dst[64] = make_float4(acc[i][4], acc[i][5], acc[i][6], acc[i][7]);
  }

  // ---- segment 2: k in [512, 1024), ascending ----
#pragma unroll
  for (int i = 0; i < 8; ++i)
#pragma unroll
    for (int j = 0; j < 8; ++j) acc[i][j] = 0.f;
  GLOAD(KSPLIT)
  SEG_LOOP(32, 64)
#undef SEG_LOOP
#undef LSTORE
#undef GLOAD

  // ---- final epilogue: C = rn(S1 + S2) ----
#pragma unroll
  for (int i = 0; i < 8; ++i) {
    const float* s1 = &C1[(size_t)(m0 + ty * 8 + i) * chunkT + nl0 + tx * 4];
    const float4 c1a = *(const float4*)&s1[0];
    const float4 c1b = *(const float4*)&s1[64];
    float* dst = &Cout[(size_t)(m0 + ty * 8 + i) * chunkT + nl0 + tx * 4];
    *(float4*)&dst[0] = make_float4(c1a.x + acc[i][0], c1a.y + acc[i][1],
                                    c1a.z + acc[i][2], c1a.w + acc[i][3]);
    *(float4*)&dst[64] = make_float4(c1b.x + acc[i][4], c1b.y + acc[i][5],
                                     c1b.z + acc[i][6], c1b.w + acc[i][7]);
  }
}

// ---------------- Scan v5: single-wave blocks, single combined input --------
#define STT 64
__global__ __launch_bounds__(64) void snn_scan_v5(const float* __restrict__ cur,
                                                  float* __restrict__ spk,
                                                  float* __restrict__ vout,
                                                  float* __restrict__ v_carry,
                                                  int t0, int chunkT, int first) {
  __shared__ float c_t[2][16][STT + 4];
  __shared__ float s_t[16][STT + 4];
  __shared__ float v_t[16][STT + 4];
  const int tid = threadIdx.x;      // 0..63
  const int n0 = blockIdx.x * 16;
  const int row = tid >> 2;         // 0..15
  const int cq = (tid & 3) * 16;    // 0,16,32,48

  float v0 = 0.0f;
  if (tid < 16 && !first) v0 = v_carry[n0 + tid];
  float leak = opaque(v0 * 0.9f);  // rn(v*0.9f); rn(0*0.9f)==0 folds reset
  float vpost = v0;

  const int nt = chunkT / STT;
  {  // prologue: tile 0 -> c_t[0]
    const float* src = &cur[(size_t)(n0 + row) * chunkT + cq];
#pragma unroll
    for (int u = 0; u < 4; ++u) *(float4*)&c_t[0][row][cq + 4 * u] = *(const float4*)&src[4 * u];
  }

  for (int it = 0; it < nt; ++it) {
    const int buf = it & 1;
    float4 p[4];
    const bool pf = (it + 1 < nt);
    if (pf) {
      const float* src = &cur[(size_t)(n0 + row) * chunkT + (it + 1) * STT + cq];
#pragma unroll
      for (int u = 0; u < 4; ++u) p[u] = *(const float4*)&src[4 * u];
    }
    if (tid < 16) {
      float cb[2][16];
      *(float4*)&cb[0][0] = *(const float4*)&c_t[buf][tid][0];
      *(float4*)&cb[0][4] = *(const float4*)&c_t[buf][tid][4];
      *(float4*)&cb[0][8] = *(const float4*)&c_t[buf][tid][8];
      *(float4*)&cb[0][12] = *(const float4*)&c_t[buf][tid][12];
#pragma unroll
      for (int g = 0; g < 4; ++g) {
        if (g < 3) {  // pipeline next group's LDS reads under the chain
          *(float4*)&cb[(g + 1) & 1][0] = *(const float4*)&c_t[buf][tid][(g + 1) * 16];
          *(float4*)&cb[(g + 1) & 1][4] = *(const float4*)&c_t[buf][tid][(g + 1) * 16 + 4];
          *(float4*)&cb[(g + 1) & 1][8] = *(const float4*)&c_t[buf][tid][(g + 1) * 16 + 8];
          *(float4*)&cb[(g + 1) & 1][12] = *(const float4*)&c_t[buf][tid][(g + 1) * 16 + 12];
        }
        float s[16], vv[16];
        const float* c = cb[g & 1];
#pragma unroll
        for (int k = 0; k < 16; ++k) {
          const float vpre = leak + c[k];        // rn(leak + c)
          const bool fired = (vpre >= 1.0f);
          const float m = opaque(vpre * 0.9f);   // rn(vpre*0.9f), off reset path
          s[k] = fired ? 1.0f : 0.0f;
          vpost = fired ? 0.0f : vpre;
          vv[k] = vpost;
          leak = fired ? 0.0f : m;               // == rn(vpost*0.9f) exactly
        }
        *(float4*)&s_t[tid][g * 16] = make_float4(s[0], s[1], s[2], s[3]);
        *(float4*)&s_t[tid][g * 16 + 4] = make_float4(s[4], s[5], s[6], s[7]);
        *(float4*)&s_t[tid][g * 16 + 8] = make_float4(s[8], s[9], s[10], s[11]);
        *(float4*)&s_t[tid][g * 16 + 12] = make_float4(s[12], s[13], s[14], s[15]);
        *(float4*)&v_t[tid][g * 16] = make_float4(vv[0], vv[1], vv[2], vv[3]);
        *(float4*)&v_t[tid][g * 16 + 4] = make_float4(vv[4], vv[5], vv[6], vv[7]);
        *(float4*)&v_t[tid][g * 16 + 8] = make_float4(vv[8], vv[9], vv[10], vv[11]);
        *(float4*)&v_t[tid][g * 16 + 12] = make_float4(vv[12], vv[13], vv[14], vv[15]);
      }
    }
    if (pf) {
#pragma unroll
      for (int u = 0; u < 4; ++u) *(float4*)&c_t[buf ^ 1][row][cq + 4 * u] = p[u];
    }
    {
      const size_t g = (size_t)(n0 + row) * SEQ_LEN + t0 + it * STT + cq;
#pragma unroll
      for (int u = 0; u < 4; ++u) {
        *(float4*)&spk[g + 4 * u] = *(const float4*)&s_t[row][cq + 4 * u];
        *(float4*)&vout[g + 4 * u] = *(const float4*)&v_t[row][cq + 4 * u];
      }
    }
  }

  if (tid < 16) v_carry[n0 + tid] = vpost;
}

// ---------------- fused fallback (ws too small), same [512|512] chain -------
__global__ __launch_bounds__(256) void snn_fused_blis(const void* __restrict__ W,
                                                      const void* __restrict__ S,
                                                      float* __restrict__ spk,
                                                      float* __restrict__ vout) {
  __shared__ float As[16][68];
  __shared__ float Bs[16][68];
  __shared__ float Ct[64][65];
  __shared__ float vsh[64];
  __shared__ int flags_sh;
  const int tid = threadIdx.x;
  const int fl = sniff_flags(W, S, tid, &flags_sh);
  const bool w_bf = (fl & 1) != 0;
  const bool s_bf = (fl & 2) != 0;

  const int tx = tid & 15;
  const int ty = tid >> 4;
  const int m0 = blockIdx.x * 64;
  if (tid < 64) vsh[tid] = 0.0f;

  for (int t0 = 0; t0 < SEQ_LEN; t0 += 64) {
    float acc0[4][4] = {{0.f}};
    float acc1[4][4] = {{0.f}};
    int k0 = 0;
#define FUSED_SEGMENT(ACC, KEND)                                                 \
    for (; k0 < (KEND); k0 += 16) {                                              \
      {                                                                          \
        const int r = tid >> 4, c = tid & 15;                                    \
        _Pragma("unroll") for (int j = 0; j < 4; ++j)                            \
            As[c][r + 16 * j] =                                                  \
                load_dyn(W, (size_t)(m0 + r + 16 * j) * N_PRE + k0 + c, w_bf);   \
      }                                                                          \
      {                                                                          \
        const int r = tid >> 6, c = tid & 63;                                    \
        _Pragma("unroll") for (int j = 0; j < 4; ++j)                            \
            Bs[r + 4 * j][c] =                                                   \
                load_dyn(S, (size_t)(k0 + r + 4 * j) * SEQ_LEN + t0 + c, s_bf);  \
      }                                                                          \
      __syncthreads();                                                           \
      _Pragma("unroll") for (int k = 0; k < 16; ++k) {                           \
        _Pragma("unroll") for (int i = 0; i < 4; ++i)                            \
            _Pragma("unroll") for (int j = 0; j < 4; ++j)                        \
                ACC[i][j] += As[k][ty * 4 + i] * Bs[k][tx * 4 + j];              \
      }                                                                          \
      __syncthreads();                                                           \
    }

    FUSED_SEGMENT(acc0, KSPLIT)
    FUSED_SEGMENT(acc1, N_PRE)
#undef FUSED_SEGMENT

#pragma unroll
    for (int i = 0; i < 4; ++i)
#pragma unroll
      for (int j = 0; j < 4; ++j) Ct[ty * 4 + i][tx * 4 + j] = acc0[i][j] + acc1[i][j];
    __syncthreads();
    if (tid < 64) {
      float v = vsh[tid];
#pragma unroll
      for (int k = 0; k < 64; ++k) {
        const float leak = opaque(v * 0.9f);
        v = leak + Ct[tid][k];
        const bool fired = (v >= 1.0f);
        const size_t g = (size_t)(m0 + tid) * SEQ_LEN + t0 + k;
        spk[g] = fired ? 1.0f : 0.0f;
        v = fired ? 0.0f : v;
        vout[g] = v;
      }
      vsh[tid] = v;
    }
    __syncthreads();
  }
}

extern "C" void kernel_launch(void* const* d_in, const int* in_sizes, int n_in,
                              void* d_out, int out_size, void* d_ws, size_t ws_size,
                              hipStream_t stream) {
  const void* stim = d_in[0];
  const void* weights = d_in[1];
  if (n_in >= 2 && in_sizes[0] == N_POST * N_PRE && in_sizes[1] == N_PRE * SEQ_LEN) {
    weights = d_in[0];
    stim = d_in[1];
  }

  float* spk = (float*)d_out;                     // output 0: spikes [N_POST, SEQ_LEN] fp32
  float* vout = spk + (size_t)N_POST * SEQ_LEN;   // output 1: v      [N_POST, SEQ_LEN] fp32

  // ws layout: [cur chunk][c1 scratch chunk][v_carry 8KB]
  const size_t carry_bytes = (size_t)N_POST * sizeof(float);
  float* v_carry = nullptr;
  size_t avail = 0;
  if (ws_size > carry_bytes + 8) {
    const size_t coff = (ws_size - carry_bytes) & ~(size_t)15;
    v_carry = (float*)((char*)d_ws + coff);
    avail = coff;
  }
  int chunkT = (int)((avail / (2 * (size_t)N_POST * sizeof(float))) / 128 * 128);
  if (chunkT > SEQ_LEN) chunkT = SEQ_LEN;

  if (chunkT >= 128) {
    float* cur = (float*)d_ws;
    float* c1 = cur + (size_t)chunkT * N_POST;
    for (int t0 = 0; t0 < SEQ_LEN; t0 += chunkT) {
      const int ct = (SEQ_LEN - t0 < chunkT) ? (SEQ_LEN - t0) : chunkT;  // mult of 128
      snn_gemm_v5<<<dim3(ct / 128, N_POST / 128), dim3(256), 0, stream>>>(weights, stim, cur,
                                                                          c1, t0, ct);
      snn_scan_v5<<<dim3(N_POST / 16), dim3(64), 0, stream>>>(cur, spk, vout, v_carry,
                                                              t0, ct, t0 == 0);
    }
  } else {
    snn_fused_blis<<<dim3(N_POST / 64), dim3(256), 0, stream>>>(weights, stim, spk, vout);
  }
}

// Round 16
// 463.680 us; speedup vs baseline: 3.5307x; 1.0433x over previous
//
#include <hip/hip_runtime.h>

#define N_PRE 1024
#define N_POST 2048
#define SEQ_LEN 4096

// Reference-verified numerics (R11..R15 PASS): per C element two fp32 segment
// chains k in [0,512) and [512,1024), ascending, single accumulator each,
// combined rn(S1+S2) (combine-at-scan-load verified in R14). stim in {0,1} ->
// products exact. Scan: v = rn(rn(v*0.9f) + c), fire >= 1.0f, reset 0
// (reset-folded form verified). DO NOT REORDER.
#define KSPLIT 512

__device__ __forceinline__ float opaque(float x) {
  asm("" : "+v"(x));
  return x;
}

__device__ __forceinline__ float load_dyn(const void* p, size_t idx, bool isbf) {
  if (isbf) {
    const unsigned short b = ((const unsigned short*)p)[idx];
    return __uint_as_float(((unsigned int)b) << 16);
  }
  return ((const float*)p)[idx];
}

// Input-dtype sniff (established: weights fp32, stim bf16; kept for safety).
__device__ __forceinline__ int sniff_flags(const void* W, const void* S, int tid,
                                           int* flags_sh) {
  if (tid < 64) {
    const unsigned short* uw = (const unsigned short*)W;
    const float f = fabsf(__uint_as_float(((unsigned int)uw[tid * 2]) << 16));
    const bool big = !(f < 64.f);
    const unsigned long long wb = __ballot(big);
    const unsigned short* us = (const unsigned short*)S;
    int hit = 0;
    for (int j = 0; j < 64; ++j) hit |= (us[tid * 128 + 2 * j] == 0x3F80u) ? 1 : 0;
    const unsigned long long sb = __ballot(hit != 0);
    if (tid == 0) *flags_sh = ((wb == 0ull) ? 1 : 0) | ((sb != 0ull) ? 2 : 0);
  }
  __syncthreads();
  return *flags_sh;
}

// ---------------- GEMM v6: 128x128, 8x8 micro, segment = blockIdx.z ---------
// 1024 blocks -> 4 blocks/CU at 128 VGPR -> 16 waves/CU (2x R15's TLP).
// Each block: 32 ascending k-tiles of one BLIS segment, raw sums to its C.
__global__ __launch_bounds__(256, 2) void snn_gemm_v6(const void* __restrict__ W,
                                                      const void* __restrict__ S,
                                                      float* __restrict__ C1,
                                                      float* __restrict__ C2,
                                                      int t0, int chunkT) {
  __shared__ float As[16][132];  // [k][m], pad 132: 16B rows + 4-bank shift
  __shared__ float Bs[16][132];  // [k][t]
  __shared__ int flags_sh;
  const int tid = threadIdx.x;
  const int fl = sniff_flags(W, S, tid, &flags_sh);
  const bool w_bf = (fl & 1) != 0;
  const bool s_bf = (fl & 2) != 0;

  const int tx = tid & 15;   // t dim
  const int ty = tid >> 4;   // m dim
  const int m0 = blockIdx.y * 128;
  const int nl0 = blockIdx.x * 128;
  const int kbase = blockIdx.z ? KSPLIT : 0;
  float* __restrict__ C = blockIdx.z ? C2 : C1;

  // staging mapping
  const int arow = tid >> 2;        // 0..63 (W row within half-tile)
  const int ac4 = (tid & 3) * 4;    // k sub-col
  const int br = tid >> 4;          // 0..15 (S row = k)
  const int bc8 = (tid & 15) * 8;   // t sub-col

  float acc[8][8] = {{0.f}};
  float4 aR0, aR1;
  uint4 bRa, bRb;

#define GLOAD(K0)                                                                \
  {                                                                              \
    if (!w_bf) {                                                                 \
      const float* Wf = (const float*)W;                                         \
      aR0 = *(const float4*)&Wf[(size_t)(m0 + arow) * N_PRE + (K0) + ac4];       \
      aR1 = *(const float4*)&Wf[(size_t)(m0 + arow + 64) * N_PRE + (K0) + ac4];  \
    }                                                                            \
    if (s_bf) {                                                                  \
      const unsigned short* Sb = (const unsigned short*)S;                       \
      bRa = *(const uint4*)&Sb[(size_t)((K0) + br) * SEQ_LEN + t0 + nl0 + bc8];  \
    } else {                                                                     \
      const float* Sf = (const float*)S;                                         \
      const size_t base = (size_t)((K0) + br) * SEQ_LEN + t0 + nl0 + bc8;        \
      bRa = *(const uint4*)&Sf[base];                                            \
      bRb = *(const uint4*)&Sf[base + 4];                                        \
    }                                                                            \
  }

#define LSTORE(K0)                                                               \
  {                                                                              \
    if (!w_bf) {                                                                 \
      As[ac4 + 0][arow] = aR0.x; As[ac4 + 1][arow] = aR0.y;                      \
      As[ac4 + 2][arow] = aR0.z; As[ac4 + 3][arow] = aR0.w;                      \
      As[ac4 + 0][arow + 64] = aR1.x; As[ac4 + 1][arow + 64] = aR1.y;            \
      As[ac4 + 2][arow + 64] = aR1.z; As[ac4 + 3][arow + 64] = aR1.w;            \
    } else {                                                                     \
      _Pragma("unroll") for (int e = 0; e < 8; ++e) {                            \
        const int idx = tid * 8 + e;                                             \
        const int m = idx >> 4, c = idx & 15;                                    \
        As[c][m] = load_dyn(W, (size_t)(m0 + m) * N_PRE + (K0) + c, true);       \
      }                                                                          \
    }                                                                            \
    if (s_bf) {                                                                  \
      float4 f0, f1;                                                             \
      f0.x = __uint_as_float(bRa.x << 16);                                       \
      f0.y = __uint_as_float(bRa.x & 0xFFFF0000u);                               \
      f0.z = __uint_as_float(bRa.y << 16);                                       \
      f0.w = __uint_as_float(bRa.y & 0xFFFF0000u);                               \
      f1.x = __uint_as_float(bRa.z << 16);                                       \
      f1.y = __uint_as_float(bRa.z & 0xFFFF0000u);                               \
      f1.z = __uint_as_float(bRa.w << 16);                                       \
      f1.w = __uint_as_float(bRa.w & 0xFFFF0000u);                               \
      *(float4*)&Bs[br][bc8] = f0;                                               \
      *(float4*)&Bs[br][bc8 + 4] = f1;                                           \
    } else {                                                                     \
      *(uint4*)&Bs[br][bc8] = bRa;                                               \
      *(uint4*)&Bs[br][bc8 + 4] = bRb;                                           \
    }                                                                            \
  }

  GLOAD(kbase)
  for (int kt = 0; kt < 32; ++kt) {
    LSTORE(kbase + kt * 16)
    __syncthreads();
    if (kt + 1 < 32) GLOAD(kbase + (kt + 1) * 16)  // issue early; compute hides it
#pragma unroll
    for (int k = 0; k < 16; ++k) {  // ascending k within tile, tiles ascending
      float a[8], b[8];
      *(float4*)&a[0] = *(const float4*)&As[k][ty * 8];
      *(float4*)&a[4] = *(const float4*)&As[k][ty * 8 + 4];
      *(float4*)&b[0] = *(const float4*)&Bs[k][tx * 4];       // cols tx*4
      *(float4*)&b[4] = *(const float4*)&Bs[k][64 + tx * 4];  // cols 64+tx*4
#pragma unroll
      for (int i = 0; i < 8; ++i)
#pragma unroll
        for (int j = 0; j < 8; ++j) acc[i][j] += a[i] * b[j];  // exact product
    }
    __syncthreads();
  }
#undef LSTORE
#undef GLOAD

  // raw segment sums (exact fp32; scan combines rn(S1+S2))
#pragma unroll
  for (int i = 0; i < 8; ++i) {
    float* dst = &C[(size_t)(m0 + ty * 8 + i) * chunkT + nl0 + tx * 4];
    *(float4*)&dst[0] = make_float4(acc[i][0], acc[i][1], acc[i][2], acc[i][3]);
    *(float4*)&dst[64] = make_float4(acc[i][4], acc[i][5], acc[i][6], acc[i][7]);
  }
}

// ---------------- Scan v6: 256 blocks x 8 neurons, load-before-store --------
// Lanes 0..7 scan; all 64 lanes stage/store. Outputs double-buffered in LDS
// and stored ONE TILE LATE, after the next tile's loads are issued, so the
// prefetch-land waits at vmcnt(stores) instead of draining them (vmcnt FIFO).
#define STT 64
__global__ __launch_bounds__(64) void snn_scan_v6(const float* __restrict__ cur1,
                                                  const float* __restrict__ cur2,
                                                  float* __restrict__ spk,
                                                  float* __restrict__ vout,
                                                  float* __restrict__ v_carry,
                                                  int t0, int chunkT, int first) {
  __shared__ float c_t[2][8][STT + 4];
  __shared__ float s_t[2][8][STT + 4];
  __shared__ float v_t[2][8][STT + 4];
  const int tid = threadIdx.x;      // 0..63
  const int n0 = blockIdx.x * 8;
  const int row = tid >> 3;         // 0..7
  const int c8 = (tid & 7) * 8;     // 0..56

  float v0 = 0.0f;
  if (tid < 8 && !first) v0 = v_carry[n0 + tid];
  float leak = opaque(v0 * 0.9f);  // rn(v*0.9f); rn(0*0.9f)==0 folds reset
  float vpost = v0;

  const int nt = chunkT / STT;
  {  // prologue: tile 0 combined -> c_t[0]
    const float* s1 = &cur1[(size_t)(n0 + row) * chunkT + c8];
    const float* s2 = &cur2[(size_t)(n0 + row) * chunkT + c8];
#pragma unroll
    for (int u = 0; u < 2; ++u) {
      const float4 a = *(const float4*)&s1[4 * u];
      const float4 b = *(const float4*)&s2[4 * u];
      *(float4*)&c_t[0][row][c8 + 4 * u] =
          make_float4(a.x + b.x, a.y + b.y, a.z + b.z, a.w + b.w);  // rn(S1+S2)
    }
  }

  for (int it = 0; it < nt; ++it) {
    const int buf = it & 1;
    float4 p1[2], p2[2];
    const bool pf = (it + 1 < nt);
    if (pf) {  // 1) issue next-tile loads FIRST (oldest vmem ops this iter)
      const float* s1 = &cur1[(size_t)(n0 + row) * chunkT + (it + 1) * STT + c8];
      const float* s2 = &cur2[(size_t)(n0 + row) * chunkT + (it + 1) * STT + c8];
#pragma unroll
      for (int u = 0; u < 2; ++u) {
        p1[u] = *(const float4*)&s1[4 * u];
        p2[u] = *(const float4*)&s2[4 * u];
      }
    }
    if (tid < 8) {  // 2) scan tile it from c_t[buf] -> s_t/v_t[buf]
      float cb[2][16];
      *(float4*)&cb[0][0] = *(const float4*)&c_t[buf][tid][0];
      *(float4*)&cb[0][4] = *(const float4*)&c_t[buf][tid][4];
      *(float4*)&cb[0][8] = *(const float4*)&c_t[buf][tid][8];
      *(float4*)&cb[0][12] = *(const float4*)&c_t[buf][tid][12];
#pragma unroll
      for (int g = 0; g < 4; ++g) {
        if (g < 3) {  // pipeline next group's LDS reads under the chain
          *(float4*)&cb[(g + 1) & 1][0] = *(const float4*)&c_t[buf][tid][(g + 1) * 16];
          *(float4*)&cb[(g + 1) & 1][4] = *(const float4*)&c_t[buf][tid][(g + 1) * 16 + 4];
          *(float4*)&cb[(g + 1) & 1][8] = *(const float4*)&c_t[buf][tid][(g + 1) * 16 + 8];
          *(float4*)&cb[(g + 1) & 1][12] = *(const float4*)&c_t[buf][tid][(g + 1) * 16 + 12];
        }
        float s[16], vv[16];
        const float* c = cb[g & 1];
#pragma unroll
        for (int k = 0; k < 16; ++k) {
          const float vpre = leak + c[k];        // rn(leak + c)
          const bool fired = (vpre >= 1.0f);
          const float m = opaque(vpre * 0.9f);   // rn(vpre*0.9f), off reset path
          s[k] = fired ? 1.0f : 0.0f;
          vpost = fired ? 0.0f : vpre;
          vv[k] = vpost;
          leak = fired ? 0.0f : m;               // == rn(vpost*0.9f) exactly
        }
        *(float4*)&s_t[buf][tid][g * 16] = make_float4(s[0], s[1], s[2], s[3]);
        *(float4*)&s_t[buf][tid][g * 16 + 4] = make_float4(s[4], s[5], s[6], s[7]);
        *(float4*)&s_t[buf][tid][g * 16 + 8] = make_float4(s[8], s[9], s[10], s[11]);
        *(float4*)&s_t[buf][tid][g * 16 + 12] = make_float4(s[12], s[13], s[14], s[15]);
        *(float4*)&v_t[buf][tid][g * 16] = make_float4(vv[0], vv[1], vv[2], vv[3]);
        *(float4*)&v_t[buf][tid][g * 16 + 4] = make_float4(vv[4], vv[5], vv[6], vv[7]);
        *(float4*)&v_t[buf][tid][g * 16 + 8] = make_float4(vv[8], vv[9], vv[10], vv[11]);
        *(float4*)&v_t[buf][tid][g * 16 + 12] = make_float4(vv[12], vv[13], vv[14], vv[15]);
      }
    }
    if (it > 0) {  // 3) store tile it-1 outputs (issued AFTER this iter's loads)
      const size_t g = (size_t)(n0 + row) * SEQ_LEN + t0 + (it - 1) * STT + c8;
#pragma unroll
      for (int u = 0; u < 2; ++u) {
        *(float4*)&spk[g + 4 * u] = *(const float4*)&s_t[buf ^ 1][row][c8 + 4 * u];
        *(float4*)&vout[g + 4 * u] = *(const float4*)&v_t[buf ^ 1][row][c8 + 4 * u];
      }
    }
    if (pf) {  // 4) land combined prefetch (waits vmcnt(stores), not 0)
#pragma unroll
      for (int u = 0; u < 2; ++u) {
        *(float4*)&c_t[buf ^ 1][row][c8 + 4 * u] =
            make_float4(p1[u].x + p2[u].x, p1[u].y + p2[u].y,
                        p1[u].z + p2[u].z, p1[u].w + p2[u].w);  // rn(S1+S2)
      }
    }
  }

  {  // drain: store last tile
    const int lb = (nt - 1) & 1;
    const size_t g = (size_t)(n0 + row) * SEQ_LEN + t0 + (nt - 1) * STT + c8;
#pragma unroll
    for (int u = 0; u < 2; ++u) {
      *(float4*)&spk[g + 4 * u] = *(const float4*)&s_t[lb][row][c8 + 4 * u];
      *(float4*)&vout[g + 4 * u] = *(const float4*)&v_t[lb][row][c8 + 4 * u];
    }
  }

  if (tid < 8) v_carry[n0 + tid] = vpost;
}

// ---------------- fused fallback (ws too small), same [512|512] chain -------
__global__ __launch_bounds__(256) void snn_fused_blis(const void* __restrict__ W,
                                                      const void* __restrict__ S,
                                                      float* __restrict__ spk,
                                                      float* __restrict__ vout) {
  __shared__ float As[16][68];
  __shared__ float Bs[16][68];
  __shared__ float Ct[64][65];
  __shared__ float vsh[64];
  __shared__ int flags_sh;
  const int tid = threadIdx.x;
  const int fl = sniff_flags(W, S, tid, &flags_sh);
  const bool w_bf = (fl & 1) != 0;
  const bool s_bf = (fl & 2) != 0;

  const int tx = tid & 15;
  const int ty = tid >> 4;
  const int m0 = blockIdx.x * 64;
  if (tid < 64) vsh[tid] = 0.0f;

  for (int t0 = 0; t0 < SEQ_LEN; t0 += 64) {
    float acc0[4][4] = {{0.f}};
    float acc1[4][4] = {{0.f}};
    int k0 = 0;
#define FUSED_SEGMENT(ACC, KEND)                                                 \
    for (; k0 < (KEND); k0 += 16) {                                              \
      {                                                                          \
        const int r = tid >> 4, c = tid & 15;                                    \
        _Pragma("unroll") for (int j = 0; j < 4; ++j)                            \
            As[c][r + 16 * j] =                                                  \
                load_dyn(W, (size_t)(m0 + r + 16 * j) * N_PRE + k0 + c, w_bf);   \
      }                                                                          \
      {                                                                          \
        const int r = tid >> 6, c = tid & 63;                                    \
        _Pragma("unroll") for (int j = 0; j < 4; ++j)                            \
            Bs[r + 4 * j][c] =                                                   \
                load_dyn(S, (size_t)(k0 + r + 4 * j) * SEQ_LEN + t0 + c, s_bf);  \
      }                                                                          \
      __syncthreads();                                                           \
      _Pragma("unroll") for (int k = 0; k < 16; ++k) {                           \
        _Pragma("unroll") for (int i = 0; i < 4; ++i)                            \
            _Pragma("unroll") for (int j = 0; j < 4; ++j)                        \
                ACC[i][j] += As[k][ty * 4 + i] * Bs[k][tx * 4 + j];              \
      }                                                                          \
      __syncthreads();                                                           \
    }

    FUSED_SEGMENT(acc0, KSPLIT)
    FUSED_SEGMENT(acc1, N_PRE)
#undef FUSED_SEGMENT

#pragma unroll
    for (int i = 0; i < 4; ++i)
#pragma unroll
      for (int j = 0; j < 4; ++j) Ct[ty * 4 + i][tx * 4 + j] = acc0[i][j] + acc1[i][j];
    __syncthreads();
    if (tid < 64) {
      float v = vsh[tid];
#pragma unroll
      for (int k = 0; k < 64; ++k) {
        const float leak = opaque(v * 0.9f);
        v = leak + Ct[tid][k];
        const bool fired = (v >= 1.0f);
        const size_t g = (size_t)(m0 + tid) * SEQ_LEN + t0 + k;
        spk[g] = fired ? 1.0f : 0.0f;
        v = fired ? 0.0f : v;
        vout[g] = v;
      }
      vsh[tid] = v;
    }
    __syncthreads();
  }
}

extern "C" void kernel_launch(void* const* d_in, const int* in_sizes, int n_in,
                              void* d_out, int out_size, void* d_ws, size_t ws_size,
                              hipStream_t stream) {
  const void* stim = d_in[0];
  const void* weights = d_in[1];
  if (n_in >= 2 && in_sizes[0] == N_POST * N_PRE && in_sizes[1] == N_PRE * SEQ_LEN) {
    weights = d_in[0];
    stim = d_in[1];
  }

  float* spk = (float*)d_out;                     // output 0: spikes [N_POST, SEQ_LEN] fp32
  float* vout = spk + (size_t)N_POST * SEQ_LEN;   // output 1: v      [N_POST, SEQ_LEN] fp32

  // ws layout: [cur1 chunk][cur2 chunk][v_carry 8KB]
  const size_t carry_bytes = (size_t)N_POST * sizeof(float);
  float* v_carry = nullptr;
  size_t avail = 0;
  if (ws_size > carry_bytes + 8) {
    const size_t coff = (ws_size - carry_bytes) & ~(size_t)15;
    v_carry = (float*)((char*)d_ws + coff);
    avail = coff;
  }
  int chunkT = (int)((avail / (2 * (size_t)N_POST * sizeof(float))) / 128 * 128);
  if (chunkT > SEQ_LEN) chunkT = SEQ_LEN;

  if (chunkT >= 128) {
    float* cur1 = (float*)d_ws;
    float* cur2 = cur1 + (size_t)chunkT * N_POST;
    for (int t0 = 0; t0 < SEQ_LEN; t0 += chunkT) {
      const int ct = (SEQ_LEN - t0 < chunkT) ? (SEQ_LEN - t0) : chunkT;  // mult of 128
      snn_gemm_v6<<<dim3(ct / 128, N_POST / 128, 2), dim3(256), 0, stream>>>(
          weights, stim, cur1, cur2, t0, ct);
      snn_scan_v6<<<dim3(N_POST / 8), dim3(64), 0, stream>>>(cur1, cur2, spk, vout,
                                                             v_carry, t0, ct, t0 == 0);
    }
  } else {
    snn_fused_blis<<<dim3(N_POST / 64), dim3(256), 0, stream>>>(weights, stim, spk, vout);
  }
}